// Round 2
// 683.657 us; speedup vs baseline: 1.0156x; 1.0156x over previous
//
#include <hip/hip_runtime.h>

// ReactantStage2: N=250000 nodes, D=256 f32, B=8192 graphs, batch sorted asc.
// out[i] = [ node_rep[i] (256 f32),
//            gate(batch[i]) ? mean(label==-1 rows of graph batch[i]) : 0 (256 f32) ]
//
// FUSED single-dispatch design (R2, compile-fixed R3):
//   One 64-lane wave per graph. Rows of a graph are contiguous (batch sorted).
//   Pass 1: stream node rows once -> copy to out node-half AND accumulate the
//           condition-mean (ballot mask replaces per-row broadcast label loads;
//           fmaf(s,v,acc) with s in {0,1} is bit-identical to the previous
//           passing kernel's conditional adds -> absmax stays 0).
//   Pass 2: store the gated mean to out pool-half (stores only).
// Traffic = 256 MB read + 512 MB write + ~2 MB ints = the HBM floor.
// NOTE: __builtin_nontemporal_* requires clang ext_vector_type, not HIP's
// uint4 class type -> u32x4/f32x4 typedefs below.

typedef unsigned long long u64;
typedef unsigned int u32x4 __attribute__((ext_vector_type(4)));
typedef float        f32x4 __attribute__((ext_vector_type(4)));

__global__ __launch_bounds__(256, 4) void fused_kernel(
    const u32x4* __restrict__ node4,      // [N,64] 16B chunks of node_rep [N,256] f32
    const int*   __restrict__ batch,      // [N] int32, sorted asc
    const int*   __restrict__ label,      // [N] int32
    const int*   __restrict__ num_graphs, // [1]
    u32x4*       __restrict__ out4,       // [N,128] 16B chunks of out [N,512] f32
    int n)
{
    int g = (blockIdx.x * blockDim.x + threadIdx.x) >> 6;
    g = __builtin_amdgcn_readfirstlane(g);   // wave-uniform by construction
    const int lane = threadIdx.x & 63;
    const int B = num_graphs[0];
    if (g >= B) return;

    // lower_bound(g) and lower_bound(g+1) over sorted batch[]
    int lo = 0, hi = n;
    while (lo < hi) { int mid = (lo + hi) >> 1; if (batch[mid] < g)     lo = mid + 1; else hi = mid; }
    const int start = lo;
    hi = n;                                   // lo already >= start
    while (lo < hi) { int mid = (lo + hi) >> 1; if (batch[mid] < g + 1) lo = mid + 1; else hi = mid; }
    const int end = lo;
    if (end <= start) return;                 // empty graph: no rows to write

    // gate: last node of the graph has label -1 (graph is non-empty here)
    const bool gate = (label[end - 1] == -1);

    // ---------------- Pass 1: copy node half + accumulate cond-sum ----------
    float ax = 0.f, ay = 0.f, az = 0.f, aw = 0.f;
    int cnt = 0;

    for (int base = start; base < end; base += 64) {
        // one coalesced vector load of up to 64 labels -> wave-wide cond mask
        const int li  = base + lane;
        const int lab = (li < end) ? label[li] : 0;   // exec-masked, no OOB
        const u64 m   = __ballot(lab == -1);
        cnt += __popcll(m);

        const int nwin = min(64, end - base);
        for (int j = 0; j < nwin; ++j) {
            const size_t i = (size_t)(base + j);
            const u32x4 v = __builtin_nontemporal_load(node4 + i * 64 + lane);
            __builtin_nontemporal_store(v, out4 + i * 128 + lane);
            const float s = (float)((unsigned)(m >> j) & 1u);  // 0.0 or 1.0
            const f32x4 f = __builtin_bit_cast(f32x4, v);
            // fmaf(1,x,a) == a+x exactly; fmaf(0,x,a) == a exactly
            ax = fmaf(s, f.x, ax);
            ay = fmaf(s, f.y, ay);
            az = fmaf(s, f.z, az);
            aw = fmaf(s, f.w, aw);
        }
    }

    // ---------------- Pass 2: broadcast gated mean to pool half -------------
    const float inv = gate ? 1.0f / (float)(cnt > 0 ? cnt : 1) : 0.0f;
    f32x4 of;
    of.x = ax * inv; of.y = ay * inv; of.z = az * inv; of.w = aw * inv;
    const u32x4 o = __builtin_bit_cast(u32x4, of);
    for (int i = start; i < end; ++i) {
        __builtin_nontemporal_store(o, out4 + (size_t)i * 128 + 64 + lane);
    }
}

extern "C" void kernel_launch(void* const* d_in, const int* in_sizes, int n_in,
                              void* d_out, int out_size, void* d_ws, size_t ws_size,
                              hipStream_t stream) {
    const float* node_rep = (const float*)d_in[0];
    const int*   batch    = (const int*)d_in[1];
    const int*   label    = (const int*)d_in[2];
    const int*   num_g    = (const int*)d_in[3];
    const int    n        = in_sizes[1];          // 250000
    const int    B_max    = 8192;                 // fixed by problem setup

    // One wave per graph, 4 waves/block -> 2048 blocks. Single dispatch.
    const int blocks = (B_max * 64 + 255) / 256;
    hipLaunchKernelGGL(fused_kernel, dim3(blocks), dim3(256), 0, stream,
                       (const u32x4*)node_rep, batch, label, num_g,
                       (u32x4*)d_out, n);
}